// Round 1
// baseline (80.902 us; speedup 1.0000x reference)
//
#include <hip/hip_runtime.h>

#define N_MENT   10000
#define BATCH    512
#define N_ANTS   50
#define EMB      1024
#define PW_EMB   64
#define IN_F     3136       // 3*EMB + PW_EMB
#define HID      128
#define M_TOT    (BATCH * N_ANTS)   // 25600
#define EPS_VAL  1e-7f
#define SLOPE    0.01f

using f32x4 = __attribute__((ext_vector_type(4))) float;
using s16x8 = __attribute__((ext_vector_type(8))) short;
using u16x8 = __attribute__((ext_vector_type(8))) unsigned short;

__device__ __forceinline__ unsigned short f2bf(float f) {
  unsigned u = __builtin_bit_cast(unsigned, f);
  u += 0x7FFFu + ((u >> 16) & 1u);   // RNE
  return (unsigned short)(u >> 16);
}

// ---- kernel 0: W1 [3136][128] f32  ->  W1t [128][3136] bf16 (transposed) ----
__global__ __launch_bounds__(256) void k_convert(const float* __restrict__ w1,
                                                 unsigned short* __restrict__ w1t) {
  int t  = blockIdx.x * 256 + threadIdx.x;   // 50176 threads total
  int n  = t & 127;
  int k0 = (t >> 7) * 8;                     // 0..3128
  u16x8 o;
  #pragma unroll
  for (int j = 0; j < 8; ++j) o[j] = f2bf(w1[(size_t)(k0 + j) * HID + n]);
  *(u16x8*)(w1t + (size_t)n * IN_F + k0) = o;
}

// ---- kernel 1: AMAB precompute ---------------------------------------------
// amab rows 0..511    : AM[b] = mentions_batch[b] . W1[   0:1024)   (f32)
// amab rows 512..10511: AB[i] = all_mentions[i]   . W1[1024:2048)   (f32)
__global__ __launch_bounds__(256) void k_amab(const float* __restrict__ all_m,
                                              const float* __restrict__ men,
                                              const unsigned short* __restrict__ w1t,
                                              float* __restrict__ amab) {
  __shared__ __align__(16) unsigned short Xs[64 * 72];
  __shared__ __align__(16) unsigned short Ws[HID * 72];

  const int t   = threadIdx.x;
  const int bid = blockIdx.x;
  const bool isAM  = (bid < 8);
  const int rowbase = isAM ? bid * 64 : (bid - 8) * 64;
  const int nrows   = isAM ? BATCH : N_MENT;
  const int wk0     = isAM ? 0 : EMB;
  const float* src  = isAM ? men : all_m;
  const int outbase = isAM ? rowbase : BATCH + rowbase;

  const int sr = t >> 2, sq = t & 3;
  const int srow = rowbase + sr;
  const float* pX = src + (size_t)(srow < nrows ? srow : 0) * EMB + sq * 16;

  const int wn = t >> 1, wh = t & 1;
  const unsigned short* pW = w1t + (size_t)wn * IN_F + wk0 + wh * 32;

  const int lane = t & 63, wid = t >> 6;
  const int ln = lane & 15, lg = lane >> 4, wcol = wid * 32;

  f32x4 acc[4][2] = {};

  for (int s = 0; s < 16; ++s) {
    const int k0 = s * 64;
    float xv[16];
    #pragma unroll
    for (int c = 0; c < 4; ++c) {
      float4 v = ((const float4*)(pX + k0))[c];
      xv[4*c+0] = v.x; xv[4*c+1] = v.y; xv[4*c+2] = v.z; xv[4*c+3] = v.w;
    }
    u16x8 p0, p1;
    #pragma unroll
    for (int j = 0; j < 8; ++j) { p0[j] = f2bf(xv[j]); p1[j] = f2bf(xv[8 + j]); }
    *(u16x8*)&Xs[sr*72 + sq*16]     = p0;
    *(u16x8*)&Xs[sr*72 + sq*16 + 8] = p1;
    #pragma unroll
    for (int c = 0; c < 4; ++c)
      *(u16x8*)&Ws[wn*72 + wh*32 + c*8] = *(const u16x8*)(pW + k0 + c*8);
    __syncthreads();
    #pragma unroll
    for (int ks = 0; ks < 2; ++ks) {
      s16x8 b0 = *(const s16x8*)&Ws[(wcol      + ln)*72 + ks*32 + lg*8];
      s16x8 b1v= *(const s16x8*)&Ws[(wcol + 16 + ln)*72 + ks*32 + lg*8];
      #pragma unroll
      for (int mf = 0; mf < 4; ++mf) {
        s16x8 a = *(const s16x8*)&Xs[(mf*16 + ln)*72 + ks*32 + lg*8];
        acc[mf][0] = __builtin_amdgcn_mfma_f32_16x16x32_bf16(a, b0,  acc[mf][0], 0, 0, 0);
        acc[mf][1] = __builtin_amdgcn_mfma_f32_16x16x32_bf16(a, b1v, acc[mf][1], 0, 0, 0);
      }
    }
    __syncthreads();
  }
  #pragma unroll
  for (int mf = 0; mf < 4; ++mf) {
    #pragma unroll
    for (int e = 0; e < 4; ++e) {
      int orow = mf*16 + lg*4 + e;
      if (rowbase + orow < nrows) {
        amab[(size_t)(outbase + orow) * HID + wcol + ln]      = acc[mf][0][e];
        amab[(size_t)(outbase + orow) * HID + wcol + 16 + ln] = acc[mf][1][e];
      }
    }
  }
}

// ---- kernel 2: main fused GEMM over k=[2048,3136) + epilogue ----------------
__global__ __launch_bounds__(256) void k_main(const float* __restrict__ all_m,
                                              const float* __restrict__ men,
                                              const float* __restrict__ pw,
                                              const int*   __restrict__ topi,
                                              const float* __restrict__ rough,
                                              const unsigned short* __restrict__ w1t,
                                              const float* __restrict__ amab,
                                              const float* __restrict__ b1,
                                              const float* __restrict__ wout,
                                              const float* __restrict__ bout,
                                              float* __restrict__ out) {
  __shared__ __align__(16) unsigned short Xs[64 * 72];
  __shared__ __align__(16) unsigned short Ws[HID * 72];
  __shared__ float red[4 * 64];

  const int t  = threadIdx.x;
  const int m0 = blockIdx.x * 64;

  // staging identity (X): row sr, 16-element quarter sq
  const int sr = t >> 2, sq = t & 3;
  const int m  = m0 + sr;
  const int bb = m / N_ANTS;
  const int idx = topi[m];
  const float* pA = men   + (size_t)bb  * EMB    + sq * 16;
  const float* pB = all_m + (size_t)idx * EMB    + sq * 16;
  const float* pP = pw    + (size_t)m   * PW_EMB + sq * 16;

  // staging identity (W)
  const int wn = t >> 1, wh = t & 1;
  const unsigned short* pW = w1t + (size_t)wn * IN_F + 2048 + wh * 32;

  // compute identity
  const int lane = t & 63, wid = t >> 6;
  const int ln = lane & 15, lg = lane >> 4, wcol = wid * 32;

  f32x4 acc[4][2] = {};

  for (int s = 0; s < 17; ++s) {          // 16 sim steps + 1 pw step, BK=64
    const int k0 = s * 64;
    float xv[16];
    if (s < 16) {                          // similarity region: a*b
      #pragma unroll
      for (int c = 0; c < 4; ++c) {
        float4 va = ((const float4*)(pA + k0))[c];
        float4 vb = ((const float4*)(pB + k0))[c];
        xv[4*c+0] = va.x * vb.x; xv[4*c+1] = va.y * vb.y;
        xv[4*c+2] = va.z * vb.z; xv[4*c+3] = va.w * vb.w;
      }
    } else {                               // pw region (exactly 64 wide)
      #pragma unroll
      for (int c = 0; c < 4; ++c) {
        float4 v = ((const float4*)pP)[c];
        xv[4*c+0] = v.x; xv[4*c+1] = v.y; xv[4*c+2] = v.z; xv[4*c+3] = v.w;
      }
    }
    u16x8 p0, p1;
    #pragma unroll
    for (int j = 0; j < 8; ++j) { p0[j] = f2bf(xv[j]); p1[j] = f2bf(xv[8 + j]); }
    *(u16x8*)&Xs[sr*72 + sq*16]     = p0;
    *(u16x8*)&Xs[sr*72 + sq*16 + 8] = p1;
    #pragma unroll
    for (int c = 0; c < 4; ++c)
      *(u16x8*)&Ws[wn*72 + wh*32 + c*8] = *(const u16x8*)(pW + k0 + c*8);
    __syncthreads();
    #pragma unroll
    for (int ks = 0; ks < 2; ++ks) {
      s16x8 b0 = *(const s16x8*)&Ws[(wcol      + ln)*72 + ks*32 + lg*8];
      s16x8 b1v= *(const s16x8*)&Ws[(wcol + 16 + ln)*72 + ks*32 + lg*8];
      #pragma unroll
      for (int mf = 0; mf < 4; ++mf) {
        s16x8 a = *(const s16x8*)&Xs[(mf*16 + ln)*72 + ks*32 + lg*8];
        acc[mf][0] = __builtin_amdgcn_mfma_f32_16x16x32_bf16(a, b0,  acc[mf][0], 0, 0, 0);
        acc[mf][1] = __builtin_amdgcn_mfma_f32_16x16x32_bf16(a, b1v, acc[mf][1], 0, 0, 0);
      }
    }
    __syncthreads();
  }

  // epilogue: + AM[b] + AB[idx] + b1, leaky, dot W_out, reduce over n
  const int n0 = wcol + ln, n1 = wcol + 16 + ln;
  const float bias0 = b1[n0], bias1 = b1[n1];
  const float w_0 = wout[n0], w_1 = wout[n1];
  #pragma unroll
  for (int mf = 0; mf < 4; ++mf) {
    #pragma unroll
    for (int e = 0; e < 4; ++e) {
      const int ml = mf*16 + lg*4 + e;
      const int gm = m0 + ml;
      const int gb = gm / N_ANTS;
      const int gi = topi[gm];
      const float* amr = amab + (size_t)gb * HID;
      const float* abr = amab + (size_t)(BATCH + gi) * HID;
      float h0 = acc[mf][0][e] + amr[n0] + abr[n0] + bias0;
      float h1 = acc[mf][1][e] + amr[n1] + abr[n1] + bias1;
      h0 = h0 > 0.f ? h0 : SLOPE * h0;
      h1 = h1 > 0.f ? h1 : SLOPE * h1;
      float ss = h0 * w_0 + h1 * w_1;
      ss += __shfl_xor(ss, 1);
      ss += __shfl_xor(ss, 2);
      ss += __shfl_xor(ss, 4);
      ss += __shfl_xor(ss, 8);
      if (ln == 0) red[wid*64 + ml] = ss;
    }
  }
  __syncthreads();
  if (t < 64) {
    const int gm = m0 + t;
    const float tot = red[t] + red[64 + t] + red[128 + t] + red[192 + t] + bout[0];
    const int gb = gm / N_ANTS;
    const int ga = gm - gb * N_ANTS;
    out[(size_t)gb * (N_ANTS + 1) + 1 + ga] = rough[gm] + tot;
  }
}

// ---- kernel 3: EPSILON dummy column ----------------------------------------
__global__ void k_eps(float* __restrict__ out) {
  out[(size_t)threadIdx.x * (N_ANTS + 1)] = EPS_VAL;
}

// ---- fallback (exact f32, used only if workspace too small) -----------------
__global__ __launch_bounds__(128) void k_fb(const float* __restrict__ all_m,
                                            const float* __restrict__ men,
                                            const float* __restrict__ pw,
                                            const int*   __restrict__ topi,
                                            const float* __restrict__ rough,
                                            const float* __restrict__ w1,
                                            const float* __restrict__ b1,
                                            const float* __restrict__ wout,
                                            const float* __restrict__ bout,
                                            float* __restrict__ out) {
  __shared__ float xs[IN_F];
  __shared__ float hred[HID];
  const int pair = blockIdx.x;
  const int t = threadIdx.x;
  const int bb = pair / N_ANTS;
  const int idx = topi[pair];
  const float* pA = men + (size_t)bb * EMB;
  const float* pB = all_m + (size_t)idx * EMB;
  for (int k = t; k < EMB; k += 128) {
    float a = pA[k], b = pB[k];
    xs[k] = a; xs[EMB + k] = b; xs[2*EMB + k] = a * b;
  }
  if (t < PW_EMB) xs[3*EMB + t] = pw[(size_t)pair * PW_EMB + t];
  __syncthreads();
  float acc = 0.f;
  for (int k = 0; k < IN_F; ++k) acc = fmaf(xs[k], w1[(size_t)k * HID + t], acc);
  acc += b1[t];
  acc = acc > 0.f ? acc : SLOPE * acc;
  hred[t] = acc * wout[t];
  __syncthreads();
  for (int off = 64; off > 0; off >>= 1) {
    if (t < off) hred[t] += hred[t + off];
    __syncthreads();
  }
  if (t == 0)
    out[(size_t)bb * (N_ANTS + 1) + 1 + (pair - bb * N_ANTS)] = rough[pair] + hred[0] + bout[0];
}

extern "C" void kernel_launch(void* const* d_in, const int* in_sizes, int n_in,
                              void* d_out, int out_size, void* d_ws, size_t ws_size,
                              hipStream_t stream) {
  const float* all_m = (const float*)d_in[0];
  const float* men   = (const float*)d_in[1];
  const float* pw    = (const float*)d_in[2];
  const int*   topi  = (const int*)  d_in[3];
  const float* rough = (const float*)d_in[4];
  const float* w1    = (const float*)d_in[5];
  const float* b1    = (const float*)d_in[6];
  const float* wout  = (const float*)d_in[7];
  const float* bout  = (const float*)d_in[8];
  float* out = (float*)d_out;

  const size_t W1T_BYTES  = (size_t)HID * IN_F * sizeof(unsigned short);      // 802816
  const size_t AMAB_BYTES = (size_t)(BATCH + N_MENT) * HID * sizeof(float);   // 5382144

  if (ws_size >= W1T_BYTES + AMAB_BYTES) {
    unsigned short* w1t = (unsigned short*)d_ws;
    float* amab = (float*)((char*)d_ws + W1T_BYTES);
    k_convert<<<196, 256, 0, stream>>>(w1, w1t);
    k_amab<<<8 + (N_MENT + 63) / 64, 256, 0, stream>>>(all_m, men, w1t, amab);
    k_eps<<<1, BATCH, 0, stream>>>(out);
    k_main<<<M_TOT / 64, 256, 0, stream>>>(all_m, men, pw, topi, rough, w1t, amab,
                                           b1, wout, bout, out);
  } else {
    k_eps<<<1, BATCH, 0, stream>>>(out);
    k_fb<<<M_TOT, 128, 0, stream>>>(all_m, men, pw, topi, rough, w1, b1, wout, bout, out);
  }
}

// Round 2
// 60.989 us; speedup vs baseline: 1.3265x; 1.3265x over previous
//
#include <hip/hip_runtime.h>

#define N_MENT   10000
#define BATCH    512
#define N_ANTS   50
#define EMB      1024
#define PW_EMB   64
#define IN_F     3136       // 3*EMB + PW_EMB
#define HID      128
#define M_TOT    (BATCH * N_ANTS)   // 25600
#define EPS_VAL  1e-7f
#define SLOPE    0.01f
#define NKT      98         // IN_F / 32 k-tiles

using f32x4 = __attribute__((ext_vector_type(4))) float;
using s16x8 = __attribute__((ext_vector_type(8))) short;
using u16x8 = __attribute__((ext_vector_type(8))) unsigned short;

__device__ __forceinline__ unsigned short f2bf(float f) {
  unsigned u = __builtin_bit_cast(unsigned, f);
  u += 0x7FFFu + ((u >> 16) & 1u);   // RNE
  return (unsigned short)(u >> 16);
}

// ---- kernel 0: W1 [3136][128] f32 -> w1f in MFMA B-fragment-linear order ----
// w1f element index = ((tn*NKT + tk)*64 + lane)*8 + j
//   where lane = ln + lg*16 holds B[col = tn*16+ln][k = tk*32 + lg*8 + j]
// so a wave's B-fragment load is one coalesced 1KB global_load_dwordx4.
__global__ __launch_bounds__(256) void k_convert(const float* __restrict__ w1,
                                                 unsigned short* __restrict__ w1f) {
  const int id   = blockIdx.x * 256 + threadIdx.x;   // 0..50175
  const int lane = id & 63;
  const int tile = id >> 6;                          // 0..783 = 8*98
  const int tk   = tile % NKT, tn = tile / NKT;
  const int n    = tn * 16 + (lane & 15);
  const int k    = tk * 32 + (lane >> 4) * 8;
  u16x8 o;
  #pragma unroll
  for (int j = 0; j < 8; ++j) o[j] = f2bf(w1[(size_t)(k + j) * HID + n]);
  *(u16x8*)(w1f + (size_t)id * 8) = o;
}

// ---- kernel 1: AMAB precompute (pipelined, BM=32) ---------------------------
// amab rows 0..511    : AM[b] = mentions_batch[b] . W1[   0:1024)
// amab rows 512..10511: AB[i] = all_mentions[i]   . W1[1024:2048)
__global__ __launch_bounds__(256) void k_amab(const float* __restrict__ all_m,
                                              const float* __restrict__ men,
                                              const unsigned short* __restrict__ w1f,
                                              float* __restrict__ amab) {
  __shared__ __align__(16) unsigned short Xs[2][32 * 72];

  const int t   = threadIdx.x;
  const int bid = blockIdx.x;
  const bool isAM   = (bid < 16);
  const int base    = isAM ? bid * 32 : (bid - 16) * 32;
  const int nrows   = isAM ? BATCH : N_MENT;
  const int tkbase  = isAM ? 0 : 32;
  const float* src  = isAM ? men : all_m;
  const int outbase = isAM ? base : BATCH + base;

  const int sr = t >> 3, sq = t & 7;
  const int srow = (base + sr < nrows) ? base + sr : nrows - 1;
  const float* pX = src + (size_t)srow * EMB + sq * 8;

  const int lane = t & 63, wid = t >> 6;
  const int ln = lane & 15, lg = lane >> 4;
  const int wcol = wid * 32;
  const size_t fb0 = ((size_t)(wid * 2)     * NKT) * 64 + lane;
  const size_t fb1 = ((size_t)(wid * 2 + 1) * NKT) * 64 + lane;

  f32x4 acc[2][2] = {};
  float4 r0 = ((const float4*)pX)[0];
  float4 r1 = ((const float4*)pX)[1];

  int buf = 0;
  for (int s = 0; s < 16; ++s) {
    u16x8 px;
    px[0]=f2bf(r0.x); px[1]=f2bf(r0.y); px[2]=f2bf(r0.z); px[3]=f2bf(r0.w);
    px[4]=f2bf(r1.x); px[5]=f2bf(r1.y); px[6]=f2bf(r1.z); px[7]=f2bf(r1.w);
    *(u16x8*)&Xs[buf][sr * 72 + sq * 8] = px;
    if (s < 15) {
      const float* q = pX + (s + 1) * 64;
      r0 = ((const float4*)q)[0];
      r1 = ((const float4*)q)[1];
    }
    __syncthreads();
    const int tkb = tkbase + s * 2;
    #pragma unroll
    for (int ks = 0; ks < 2; ++ks) {
      s16x8 bf0 = *(const s16x8*)(w1f + (fb0 + (size_t)(tkb + ks) * 64) * 8);
      s16x8 bf1 = *(const s16x8*)(w1f + (fb1 + (size_t)(tkb + ks) * 64) * 8);
      #pragma unroll
      for (int mf = 0; mf < 2; ++mf) {
        s16x8 a = *(const s16x8*)&Xs[buf][(mf * 16 + ln) * 72 + ks * 32 + lg * 8];
        acc[mf][0] = __builtin_amdgcn_mfma_f32_16x16x32_bf16(a, bf0, acc[mf][0], 0, 0, 0);
        acc[mf][1] = __builtin_amdgcn_mfma_f32_16x16x32_bf16(a, bf1, acc[mf][1], 0, 0, 0);
      }
    }
    buf ^= 1;
  }
  #pragma unroll
  for (int mf = 0; mf < 2; ++mf)
    #pragma unroll
    for (int e = 0; e < 4; ++e) {
      const int r = mf * 16 + lg * 4 + e;
      if (base + r < nrows) {
        amab[(size_t)(outbase + r) * HID + wcol + ln]      = acc[mf][0][e];
        amab[(size_t)(outbase + r) * HID + wcol + 16 + ln] = acc[mf][1][e];
      }
    }
}

// ---- kernel 2: main fused GEMM over k=[2048,3136) + epilogue (BM=32) --------
__global__ __launch_bounds__(256) void k_main(const float* __restrict__ all_m,
                                              const float* __restrict__ men,
                                              const float* __restrict__ pw,
                                              const int*   __restrict__ topi,
                                              const float* __restrict__ rough,
                                              const unsigned short* __restrict__ w1f,
                                              const float* __restrict__ amab,
                                              const float* __restrict__ b1,
                                              const float* __restrict__ wout,
                                              const float* __restrict__ bout,
                                              float* __restrict__ out) {
  __shared__ __align__(16) unsigned short Xs[2][32 * 72];
  __shared__ float red[4 * 32];

  const int t  = threadIdx.x;
  const int m0 = blockIdx.x * 32;

  const int sr = t >> 3, sq = t & 7;
  const int m  = m0 + sr;
  const int bb = m / N_ANTS;
  const int bidx = topi[m];
  const float* pA = men   + (size_t)bb   * EMB    + sq * 8;
  const float* pB = all_m + (size_t)bidx * EMB    + sq * 8;
  const float* pP = pw    + (size_t)m    * PW_EMB + sq * 8;

  const int lane = t & 63, wid = t >> 6;
  const int ln = lane & 15, lg = lane >> 4;
  const int wcol = wid * 32;
  const size_t fb0 = ((size_t)(wid * 2)     * NKT) * 64 + lane;
  const size_t fb1 = ((size_t)(wid * 2 + 1) * NKT) * 64 + lane;

  f32x4 acc[2][2] = {};

  float4 ra0 = ((const float4*)pA)[0];
  float4 ra1 = ((const float4*)pA)[1];
  float4 rb0 = ((const float4*)pB)[0];
  float4 rb1 = ((const float4*)pB)[1];

  int buf = 0;
  // 16 similarity steps (k=2048..3071) + 1 pw step (k=3072..3135), BK=64 each.
  for (int s = 0; s < 17; ++s) {
    u16x8 px;
    px[0]=f2bf(ra0.x*rb0.x); px[1]=f2bf(ra0.y*rb0.y);
    px[2]=f2bf(ra0.z*rb0.z); px[3]=f2bf(ra0.w*rb0.w);
    px[4]=f2bf(ra1.x*rb1.x); px[5]=f2bf(ra1.y*rb1.y);
    px[6]=f2bf(ra1.z*rb1.z); px[7]=f2bf(ra1.w*rb1.w);
    *(u16x8*)&Xs[buf][sr * 72 + sq * 8] = px;

    if (s < 15) {                       // prefetch next similarity step
      const float* qA = pA + (s + 1) * 64;
      const float* qB = pB + (s + 1) * 64;
      ra0 = ((const float4*)qA)[0]; ra1 = ((const float4*)qA)[1];
      rb0 = ((const float4*)qB)[0]; rb1 = ((const float4*)qB)[1];
    } else if (s == 15) {               // prefetch pw step; multiply by 1.0
      ra0 = ((const float4*)pP)[0];  ra1 = ((const float4*)pP)[1];
      rb0 = make_float4(1.f, 1.f, 1.f, 1.f); rb1 = rb0;
    }
    __syncthreads();

    const int tkb = 64 + s * 2;         // k-tile base (2048/32 = 64)
    #pragma unroll
    for (int ks = 0; ks < 2; ++ks) {
      s16x8 bf0 = *(const s16x8*)(w1f + (fb0 + (size_t)(tkb + ks) * 64) * 8);
      s16x8 bf1 = *(const s16x8*)(w1f + (fb1 + (size_t)(tkb + ks) * 64) * 8);
      #pragma unroll
      for (int mf = 0; mf < 2; ++mf) {
        s16x8 a = *(const s16x8*)&Xs[buf][(mf * 16 + ln) * 72 + ks * 32 + lg * 8];
        acc[mf][0] = __builtin_amdgcn_mfma_f32_16x16x32_bf16(a, bf0, acc[mf][0], 0, 0, 0);
        acc[mf][1] = __builtin_amdgcn_mfma_f32_16x16x32_bf16(a, bf1, acc[mf][1], 0, 0, 0);
      }
    }
    buf ^= 1;
  }

  // epilogue: + AM[b] + AB[idx] + b1, leaky, dot W_out, reduce over n
  const int n0 = wcol + ln, n1 = wcol + 16 + ln;
  const float bias0 = b1[n0], bias1 = b1[n1];
  const float w_0 = wout[n0], w_1 = wout[n1];
  #pragma unroll
  for (int mf = 0; mf < 2; ++mf)
    #pragma unroll
    for (int e = 0; e < 4; ++e) {
      const int ml = mf * 16 + lg * 4 + e;
      const int gm = m0 + ml;
      const int gb = gm / N_ANTS;
      const int gi = topi[gm];
      const float* amr = amab + (size_t)gb * HID;
      const float* abr = amab + (size_t)(BATCH + gi) * HID;
      float h0 = acc[mf][0][e] + amr[n0] + abr[n0] + bias0;
      float h1 = acc[mf][1][e] + amr[n1] + abr[n1] + bias1;
      h0 = h0 > 0.f ? h0 : SLOPE * h0;
      h1 = h1 > 0.f ? h1 : SLOPE * h1;
      float ss = h0 * w_0 + h1 * w_1;
      ss += __shfl_xor(ss, 1);
      ss += __shfl_xor(ss, 2);
      ss += __shfl_xor(ss, 4);
      ss += __shfl_xor(ss, 8);
      if (ln == 0) red[wid * 32 + ml] = ss;
    }
  __syncthreads();
  if (t < 32) {
    const int gm = m0 + t;
    const int gb = gm / N_ANTS;
    const int ga = gm - gb * N_ANTS;
    out[(size_t)gb * (N_ANTS + 1) + 1 + ga] =
        rough[gm] + red[t] + red[32 + t] + red[64 + t] + red[96 + t] + bout[0];
  }
  if (t == 0) {   // EPSILON dummy column (duplicate writes of same value are benign)
    for (int g = m0 / N_ANTS; g <= (m0 + 31) / N_ANTS; ++g)
      out[(size_t)g * (N_ANTS + 1)] = EPS_VAL;
  }
}

// ---- fallback (exact f32, used only if workspace too small) -----------------
__global__ void k_eps(float* __restrict__ out) {
  out[(size_t)threadIdx.x * (N_ANTS + 1)] = EPS_VAL;
}

__global__ __launch_bounds__(128) void k_fb(const float* __restrict__ all_m,
                                            const float* __restrict__ men,
                                            const float* __restrict__ pw,
                                            const int*   __restrict__ topi,
                                            const float* __restrict__ rough,
                                            const float* __restrict__ w1,
                                            const float* __restrict__ b1,
                                            const float* __restrict__ wout,
                                            const float* __restrict__ bout,
                                            float* __restrict__ out) {
  __shared__ float xs[IN_F];
  __shared__ float hred[HID];
  const int pair = blockIdx.x;
  const int t = threadIdx.x;
  const int bb = pair / N_ANTS;
  const int idx = topi[pair];
  const float* pA = men + (size_t)bb * EMB;
  const float* pB = all_m + (size_t)idx * EMB;
  for (int k = t; k < EMB; k += 128) {
    float a = pA[k], b = pB[k];
    xs[k] = a; xs[EMB + k] = b; xs[2 * EMB + k] = a * b;
  }
  if (t < PW_EMB) xs[3 * EMB + t] = pw[(size_t)pair * PW_EMB + t];
  __syncthreads();
  float acc = 0.f;
  for (int k = 0; k < IN_F; ++k) acc = fmaf(xs[k], w1[(size_t)k * HID + t], acc);
  acc += b1[t];
  acc = acc > 0.f ? acc : SLOPE * acc;
  hred[t] = acc * wout[t];
  __syncthreads();
  for (int off = 64; off > 0; off >>= 1) {
    if (t < off) hred[t] += hred[t + off];
    __syncthreads();
  }
  if (t == 0)
    out[(size_t)bb * (N_ANTS + 1) + 1 + (pair - bb * N_ANTS)] = rough[pair] + hred[0] + bout[0];
}

extern "C" void kernel_launch(void* const* d_in, const int* in_sizes, int n_in,
                              void* d_out, int out_size, void* d_ws, size_t ws_size,
                              hipStream_t stream) {
  const float* all_m = (const float*)d_in[0];
  const float* men   = (const float*)d_in[1];
  const float* pw    = (const float*)d_in[2];
  const int*   topi  = (const int*)  d_in[3];
  const float* rough = (const float*)d_in[4];
  const float* w1    = (const float*)d_in[5];
  const float* b1    = (const float*)d_in[6];
  const float* wout  = (const float*)d_in[7];
  const float* bout  = (const float*)d_in[8];
  float* out = (float*)d_out;

  const size_t W1F_BYTES  = (size_t)HID * IN_F * sizeof(unsigned short);      // 802816
  const size_t AMAB_BYTES = (size_t)(BATCH + N_MENT) * HID * sizeof(float);   // 5382144

  if (ws_size >= W1F_BYTES + AMAB_BYTES) {
    unsigned short* w1f = (unsigned short*)d_ws;
    float* amab = (float*)((char*)d_ws + W1F_BYTES);
    k_convert<<<196, 256, 0, stream>>>(w1, w1f);
    k_amab<<<16 + (N_MENT + 31) / 32, 256, 0, stream>>>(all_m, men, w1f, amab);
    k_main<<<M_TOT / 32, 256, 0, stream>>>(all_m, men, pw, topi, rough, w1f, amab,
                                           b1, wout, bout, out);
  } else {
    k_eps<<<1, BATCH, 0, stream>>>(out);
    k_fb<<<M_TOT, 128, 0, stream>>>(all_m, men, pw, topi, rough, w1, b1, wout, bout, out);
  }
}

// Round 3
// 52.705 us; speedup vs baseline: 1.5350x; 1.1572x over previous
//
#include <hip/hip_runtime.h>

#define N_MENT   10000
#define BATCH    512
#define N_ANTS   50
#define EMB      1024
#define PW_EMB   64
#define IN_F     3136       // 3*EMB + PW_EMB
#define HID      128
#define M_TOT    (BATCH * N_ANTS)   // 25600
#define EPS_VAL  1e-7f
#define SLOPE    0.01f
#define NKT      98         // IN_F / 32 k-tiles

using f32x4 = __attribute__((ext_vector_type(4))) float;
using s16x8 = __attribute__((ext_vector_type(8))) short;
using u16x8 = __attribute__((ext_vector_type(8))) unsigned short;

__device__ __forceinline__ unsigned short f2bf(float f) {
  unsigned u = __builtin_bit_cast(unsigned, f);
  u += 0x7FFFu + ((u >> 16) & 1u);   // RNE
  return (unsigned short)(u >> 16);
}

// ---- kernel 0: W1 [3136][128] f32 -> w1f in MFMA B-fragment-linear order ----
// w1f element index = ((tn*NKT + tk)*64 + lane)*8 + j
//   where lane = ln + lg*16 holds B[col = tn*16+ln][k = tk*32 + lg*8 + j]
__global__ __launch_bounds__(256) void k_convert(const float* __restrict__ w1,
                                                 unsigned short* __restrict__ w1f) {
  const int id   = blockIdx.x * 256 + threadIdx.x;   // 0..50175
  const int lane = id & 63;
  const int tile = id >> 6;                          // 0..783 = 8*98
  const int tk   = tile % NKT, tn = tile / NKT;
  const int n    = tn * 16 + (lane & 15);
  const int k    = tk * 32 + (lane >> 4) * 8;
  u16x8 o;
  #pragma unroll
  for (int j = 0; j < 8; ++j) o[j] = f2bf(w1[(size_t)(k + j) * HID + n]);
  *(u16x8*)(w1f + (size_t)id * 8) = o;
}

// ---- kernel 1: AMAB precompute (reg-prefetched pipeline, BM=32) -------------
// amab rows 0..511    : AM[b] = mentions_batch[b] . W1[   0:1024)
// amab rows 512..10511: AB[i] = all_mentions[i]   . W1[1024:2048)
__global__ __launch_bounds__(256) void k_amab(const float* __restrict__ all_m,
                                              const float* __restrict__ men,
                                              const unsigned short* __restrict__ w1f,
                                              float* __restrict__ amab) {
  __shared__ __align__(16) unsigned short Xs[2][32 * 72];

  const int t   = threadIdx.x;
  const int bid = blockIdx.x;
  const bool isAM   = (bid < 16);
  const int base    = isAM ? bid * 32 : (bid - 16) * 32;
  const int nrows   = isAM ? BATCH : N_MENT;
  const int tkbase  = isAM ? 0 : 32;
  const float* src  = isAM ? men : all_m;
  const int outbase = isAM ? base : BATCH + base;

  const int sr = t >> 3, sq = t & 7;
  const int srow = (base + sr < nrows) ? base + sr : nrows - 1;
  const float* pX = src + (size_t)srow * EMB + sq * 8;

  const int lane = t & 63, wid = t >> 6;
  const int ln = lane & 15, lg = lane >> 4;
  const int wcol = wid * 32;
  const unsigned short* wf0 = w1f + (((size_t)(wid * 2)     * NKT) * 64 + lane) * 8;
  const unsigned short* wf1 = w1f + (((size_t)(wid * 2 + 1) * NKT) * 64 + lane) * 8;

  f32x4 acc[2][2] = {};

  float4 r0 = ((const float4*)pX)[0];
  float4 r1 = ((const float4*)pX)[1];
  s16x8 bc00 = *(const s16x8*)(wf0 + (size_t)(tkbase)     * 512);
  s16x8 bc01 = *(const s16x8*)(wf1 + (size_t)(tkbase)     * 512);
  s16x8 bc10 = *(const s16x8*)(wf0 + (size_t)(tkbase + 1) * 512);
  s16x8 bc11 = *(const s16x8*)(wf1 + (size_t)(tkbase + 1) * 512);

  int buf = 0;
  for (int s = 0; s < 16; ++s) {
    u16x8 px;
    px[0]=f2bf(r0.x); px[1]=f2bf(r0.y); px[2]=f2bf(r0.z); px[3]=f2bf(r0.w);
    px[4]=f2bf(r1.x); px[5]=f2bf(r1.y); px[6]=f2bf(r1.z); px[7]=f2bf(r1.w);
    *(u16x8*)&Xs[buf][sr * 72 + sq * 8] = px;

    if (s < 15) {                       // prefetch next X step
      const float* q = pX + (s + 1) * 64;
      r0 = ((const float4*)q)[0];
      r1 = ((const float4*)q)[1];
    }
    // prefetch next step's B fragments (clamped at the end; redundant reload)
    const int tkn = tkbase + (s < 15 ? (s + 1) : s) * 2;
    s16x8 bn00 = *(const s16x8*)(wf0 + (size_t)(tkn)     * 512);
    s16x8 bn01 = *(const s16x8*)(wf1 + (size_t)(tkn)     * 512);
    s16x8 bn10 = *(const s16x8*)(wf0 + (size_t)(tkn + 1) * 512);
    s16x8 bn11 = *(const s16x8*)(wf1 + (size_t)(tkn + 1) * 512);

    __syncthreads();
    #pragma unroll
    for (int mf = 0; mf < 2; ++mf) {
      s16x8 a0 = *(const s16x8*)&Xs[buf][(mf * 16 + ln) * 72 + lg * 8];
      s16x8 a1 = *(const s16x8*)&Xs[buf][(mf * 16 + ln) * 72 + 32 + lg * 8];
      acc[mf][0] = __builtin_amdgcn_mfma_f32_16x16x32_bf16(a0, bc00, acc[mf][0], 0, 0, 0);
      acc[mf][1] = __builtin_amdgcn_mfma_f32_16x16x32_bf16(a0, bc01, acc[mf][1], 0, 0, 0);
      acc[mf][0] = __builtin_amdgcn_mfma_f32_16x16x32_bf16(a1, bc10, acc[mf][0], 0, 0, 0);
      acc[mf][1] = __builtin_amdgcn_mfma_f32_16x16x32_bf16(a1, bc11, acc[mf][1], 0, 0, 0);
    }
    bc00 = bn00; bc01 = bn01; bc10 = bn10; bc11 = bn11;
    buf ^= 1;
  }
  #pragma unroll
  for (int mf = 0; mf < 2; ++mf)
    #pragma unroll
    for (int e = 0; e < 4; ++e) {
      const int r = mf * 16 + lg * 4 + e;
      if (base + r < nrows) {
        amab[(size_t)(outbase + r) * HID + wcol + ln]      = acc[mf][0][e];
        amab[(size_t)(outbase + r) * HID + wcol + 16 + ln] = acc[mf][1][e];
      }
    }
}

// ---- kernel 2: main fused GEMM over k=[2048,3136) + epilogue (BM=32) --------
__global__ __launch_bounds__(256) void k_main(const float* __restrict__ all_m,
                                              const float* __restrict__ men,
                                              const float* __restrict__ pw,
                                              const int*   __restrict__ topi,
                                              const float* __restrict__ rough,
                                              const unsigned short* __restrict__ w1f,
                                              const float* __restrict__ amab,
                                              const float* __restrict__ b1,
                                              const float* __restrict__ wout,
                                              const float* __restrict__ bout,
                                              float* __restrict__ out) {
  __shared__ __align__(16) unsigned short Xs[2][32 * 72];
  __shared__ float red[4 * 32];

  const int t  = threadIdx.x;
  const int m0 = blockIdx.x * 32;

  const int sr = t >> 3, sq = t & 7;
  const int m  = m0 + sr;
  const int bb = m / N_ANTS;
  const int bidx = topi[m];
  const float* pA = men   + (size_t)bb   * EMB    + sq * 8;
  const float* pB = all_m + (size_t)bidx * EMB    + sq * 8;
  const float* pP = pw    + (size_t)m    * PW_EMB + sq * 8;

  const int lane = t & 63, wid = t >> 6;
  const int ln = lane & 15, lg = lane >> 4;
  const int wcol = wid * 32;
  const unsigned short* wf0 = w1f + (((size_t)(wid * 2)     * NKT) * 64 + lane) * 8;
  const unsigned short* wf1 = w1f + (((size_t)(wid * 2 + 1) * NKT) * 64 + lane) * 8;

  f32x4 acc[2][2] = {};

  float4 ra0 = ((const float4*)pA)[0];
  float4 ra1 = ((const float4*)pA)[1];
  float4 rb0 = ((const float4*)pB)[0];
  float4 rb1 = ((const float4*)pB)[1];
  s16x8 bc00 = *(const s16x8*)(wf0 + (size_t)(64)     * 512);
  s16x8 bc01 = *(const s16x8*)(wf1 + (size_t)(64)     * 512);
  s16x8 bc10 = *(const s16x8*)(wf0 + (size_t)(64 + 1) * 512);
  s16x8 bc11 = *(const s16x8*)(wf1 + (size_t)(64 + 1) * 512);

  int buf = 0;
  // 16 similarity steps (k=2048..3071) + 1 pw step (k=3072..3135), BK=64 each.
  for (int s = 0; s < 17; ++s) {
    u16x8 px;
    px[0]=f2bf(ra0.x*rb0.x); px[1]=f2bf(ra0.y*rb0.y);
    px[2]=f2bf(ra0.z*rb0.z); px[3]=f2bf(ra0.w*rb0.w);
    px[4]=f2bf(ra1.x*rb1.x); px[5]=f2bf(ra1.y*rb1.y);
    px[6]=f2bf(ra1.z*rb1.z); px[7]=f2bf(ra1.w*rb1.w);
    *(u16x8*)&Xs[buf][sr * 72 + sq * 8] = px;

    if (s < 15) {                       // prefetch next similarity step
      const float* qA = pA + (s + 1) * 64;
      const float* qB = pB + (s + 1) * 64;
      ra0 = ((const float4*)qA)[0]; ra1 = ((const float4*)qA)[1];
      rb0 = ((const float4*)qB)[0]; rb1 = ((const float4*)qB)[1];
    } else if (s == 15) {               // prefetch pw step; multiply by 1.0
      ra0 = ((const float4*)pP)[0];  ra1 = ((const float4*)pP)[1];
      rb0 = make_float4(1.f, 1.f, 1.f, 1.f); rb1 = rb0;
    }
    // prefetch next step's B fragments (clamped at the end)
    const int tkn = 64 + (s < 16 ? (s + 1) : s) * 2;
    s16x8 bn00 = *(const s16x8*)(wf0 + (size_t)(tkn)     * 512);
    s16x8 bn01 = *(const s16x8*)(wf1 + (size_t)(tkn)     * 512);
    s16x8 bn10 = *(const s16x8*)(wf0 + (size_t)(tkn + 1) * 512);
    s16x8 bn11 = *(const s16x8*)(wf1 + (size_t)(tkn + 1) * 512);

    __syncthreads();
    #pragma unroll
    for (int mf = 0; mf < 2; ++mf) {
      s16x8 a0 = *(const s16x8*)&Xs[buf][(mf * 16 + ln) * 72 + lg * 8];
      s16x8 a1 = *(const s16x8*)&Xs[buf][(mf * 16 + ln) * 72 + 32 + lg * 8];
      acc[mf][0] = __builtin_amdgcn_mfma_f32_16x16x32_bf16(a0, bc00, acc[mf][0], 0, 0, 0);
      acc[mf][1] = __builtin_amdgcn_mfma_f32_16x16x32_bf16(a0, bc01, acc[mf][1], 0, 0, 0);
      acc[mf][0] = __builtin_amdgcn_mfma_f32_16x16x32_bf16(a1, bc10, acc[mf][0], 0, 0, 0);
      acc[mf][1] = __builtin_amdgcn_mfma_f32_16x16x32_bf16(a1, bc11, acc[mf][1], 0, 0, 0);
    }
    bc00 = bn00; bc01 = bn01; bc10 = bn10; bc11 = bn11;
    buf ^= 1;
  }

  // epilogue: + AM[b] + AB[idx] + b1, leaky, dot W_out, reduce over n
  const int n0 = wcol + ln, n1 = wcol + 16 + ln;
  const float bias0 = b1[n0], bias1 = b1[n1];
  const float w_0 = wout[n0], w_1 = wout[n1];
  #pragma unroll
  for (int mf = 0; mf < 2; ++mf)
    #pragma unroll
    for (int e = 0; e < 4; ++e) {
      const int ml = mf * 16 + lg * 4 + e;
      const int gm = m0 + ml;
      const int gb = gm / N_ANTS;
      const int gi = topi[gm];
      const float* amr = amab + (size_t)gb * HID;
      const float* abr = amab + (size_t)(BATCH + gi) * HID;
      float h0 = acc[mf][0][e] + amr[n0] + abr[n0] + bias0;
      float h1 = acc[mf][1][e] + amr[n1] + abr[n1] + bias1;
      h0 = h0 > 0.f ? h0 : SLOPE * h0;
      h1 = h1 > 0.f ? h1 : SLOPE * h1;
      float ss = h0 * w_0 + h1 * w_1;
      ss += __shfl_xor(ss, 1);
      ss += __shfl_xor(ss, 2);
      ss += __shfl_xor(ss, 4);
      ss += __shfl_xor(ss, 8);
      if (ln == 0) red[wid * 32 + ml] = ss;
    }
  __syncthreads();
  if (t < 32) {
    const int gm = m0 + t;
    const int gb = gm / N_ANTS;
    const int ga = gm - gb * N_ANTS;
    out[(size_t)gb * (N_ANTS + 1) + 1 + ga] =
        rough[gm] + red[t] + red[32 + t] + red[64 + t] + red[96 + t] + bout[0];
  }
  if (t == 0) {   // EPSILON dummy column (duplicate writes of same value are benign)
    for (int g = m0 / N_ANTS; g <= (m0 + 31) / N_ANTS; ++g)
      out[(size_t)g * (N_ANTS + 1)] = EPS_VAL;
  }
}

// ---- fallback (exact f32, used only if workspace too small) -----------------
__global__ void k_eps(float* __restrict__ out) {
  out[(size_t)threadIdx.x * (N_ANTS + 1)] = EPS_VAL;
}

__global__ __launch_bounds__(128) void k_fb(const float* __restrict__ all_m,
                                            const float* __restrict__ men,
                                            const float* __restrict__ pw,
                                            const int*   __restrict__ topi,
                                            const float* __restrict__ rough,
                                            const float* __restrict__ w1,
                                            const float* __restrict__ b1,
                                            const float* __restrict__ wout,
                                            const float* __restrict__ bout,
                                            float* __restrict__ out) {
  __shared__ float xs[IN_F];
  __shared__ float hred[HID];
  const int pair = blockIdx.x;
  const int t = threadIdx.x;
  const int bb = pair / N_ANTS;
  const int idx = topi[pair];
  const float* pA = men + (size_t)bb * EMB;
  const float* pB = all_m + (size_t)idx * EMB;
  for (int k = t; k < EMB; k += 128) {
    float a = pA[k], b = pB[k];
    xs[k] = a; xs[EMB + k] = b; xs[2 * EMB + k] = a * b;
  }
  if (t < PW_EMB) xs[3 * EMB + t] = pw[(size_t)pair * PW_EMB + t];
  __syncthreads();
  float acc = 0.f;
  for (int k = 0; k < IN_F; ++k) acc = fmaf(xs[k], w1[(size_t)k * HID + t], acc);
  acc += b1[t];
  acc = acc > 0.f ? acc : SLOPE * acc;
  hred[t] = acc * wout[t];
  __syncthreads();
  for (int off = 64; off > 0; off >>= 1) {
    if (t < off) hred[t] += hred[t + off];
    __syncthreads();
  }
  if (t == 0)
    out[(size_t)bb * (N_ANTS + 1) + 1 + (pair - bb * N_ANTS)] = rough[pair] + hred[0] + bout[0];
}

extern "C" void kernel_launch(void* const* d_in, const int* in_sizes, int n_in,
                              void* d_out, int out_size, void* d_ws, size_t ws_size,
                              hipStream_t stream) {
  const float* all_m = (const float*)d_in[0];
  const float* men   = (const float*)d_in[1];
  const float* pw    = (const float*)d_in[2];
  const int*   topi  = (const int*)  d_in[3];
  const float* rough = (const float*)d_in[4];
  const float* w1    = (const float*)d_in[5];
  const float* b1    = (const float*)d_in[6];
  const float* wout  = (const float*)d_in[7];
  const float* bout  = (const float*)d_in[8];
  float* out = (float*)d_out;

  const size_t W1F_BYTES  = (size_t)HID * IN_F * sizeof(unsigned short);      // 802816
  const size_t AMAB_BYTES = (size_t)(BATCH + N_MENT) * HID * sizeof(float);   // 5382144

  if (ws_size >= W1F_BYTES + AMAB_BYTES) {
    unsigned short* w1f = (unsigned short*)d_ws;
    float* amab = (float*)((char*)d_ws + W1F_BYTES);
    k_convert<<<196, 256, 0, stream>>>(w1, w1f);
    k_amab<<<16 + (N_MENT + 31) / 32, 256, 0, stream>>>(all_m, men, w1f, amab);
    k_main<<<M_TOT / 32, 256, 0, stream>>>(all_m, men, pw, topi, rough, w1f, amab,
                                           b1, wout, bout, out);
  } else {
    k_eps<<<1, BATCH, 0, stream>>>(out);
    k_fb<<<M_TOT, 128, 0, stream>>>(all_m, men, pw, topi, rough, w1, b1, wout, bout, out);
  }
}